// Round 8
// baseline (587.532 us; speedup 1.0000x reference)
//
#include <hip/hip_runtime.h>
#include <float.h>

#define BB 16
#define NN 4096
#define CC 64
#define KNN 32
#define NPART 4
#define PSZ 1024   // NN / NPART
#define NQ 65536   // BB * NN

// ===========================================================================
// KNN, reference arithmetic VARIANT V2 (verified bit-compatible in R4):
//   dot = fma(z,z', fma(y,y', x*x'));  xx = ((x*x + y*y) + z*z)  [rn, no fma]
//   pd  = ((dot+dot) - xx_q) - xx_c    [left-assoc rn]
// Largest pd = nearest.
//
// R8: R5-R7 select issued ~84 VALU/iter vs ~39 in source at VGPR_Count=24:
// allocator targets 8 waves/EU (64 regs/wave = 24 arch + AGPR home for the
// heap, accvgpr_read/write around every med3 — even with "+v" asm, which
// only forces the VALUE into a v-reg at the asm site, not its home).
// Fix: amdgpu_waves_per_eu(2,4) caps the occupancy target at 4 waves/EU
// (grid gives only 4 anyway) -> 128-reg arch budget -> heap lives in VGPRs.
// Merge kernel also rewritten LDS-free (was 33KB/block -> 1 wave/SIMD).
// ===========================================================================

// h_t = med3(pd, h_t, h_{t-1}), t = 31..1 (reads pre-update h_{t-1}),
// then h00 = max(h00, pd). Asm pins all operands to arch VGPRs.
#define INS1(ht, hm) asm("v_med3_f32 %0, %1, %0, %2" : "+v"(ht) : "v"(pd), "v"(hm));
#define INS_CHAIN \
  INS1(h31,h30) INS1(h30,h29) INS1(h29,h28) INS1(h28,h27) \
  INS1(h27,h26) INS1(h26,h25) INS1(h25,h24) INS1(h24,h23) \
  INS1(h23,h22) INS1(h22,h21) INS1(h21,h20) INS1(h20,h19) \
  INS1(h19,h18) INS1(h18,h17) INS1(h17,h16) INS1(h16,h15) \
  INS1(h15,h14) INS1(h14,h13) INS1(h13,h12) INS1(h12,h11) \
  INS1(h11,h10) INS1(h10,h09) INS1(h09,h08) INS1(h08,h07) \
  INS1(h07,h06) INS1(h06,h05) INS1(h05,h04) INS1(h04,h03) \
  INS1(h03,h02) INS1(h02,h01) INS1(h01,h00) \
  asm("v_max_f32 %0, %1, %0" : "+v"(h00) : "v"(pd));

#define H_DECL \
  float h00=-FLT_MAX,h01=-FLT_MAX,h02=-FLT_MAX,h03=-FLT_MAX, \
        h04=-FLT_MAX,h05=-FLT_MAX,h06=-FLT_MAX,h07=-FLT_MAX, \
        h08=-FLT_MAX,h09=-FLT_MAX,h10=-FLT_MAX,h11=-FLT_MAX, \
        h12=-FLT_MAX,h13=-FLT_MAX,h14=-FLT_MAX,h15=-FLT_MAX, \
        h16=-FLT_MAX,h17=-FLT_MAX,h18=-FLT_MAX,h19=-FLT_MAX, \
        h20=-FLT_MAX,h21=-FLT_MAX,h22=-FLT_MAX,h23=-FLT_MAX, \
        h24=-FLT_MAX,h25=-FLT_MAX,h26=-FLT_MAX,h27=-FLT_MAX, \
        h28=-FLT_MAX,h29=-FLT_MAX,h30=-FLT_MAX,h31=-FLT_MAX;

// --------------------------------------------------------------------------
// A: grid 1024 = (b<<6)|(g<<2)|p, 256 thr = 256 queries. LDS = 16KB partition.
// --------------------------------------------------------------------------
__global__ __launch_bounds__(256)
__attribute__((amdgpu_waves_per_eu(2, 4)))
void knn_select_kernel(const float* __restrict__ xyz,
                       float* __restrict__ val_buf) {
#pragma clang fp contract(off)
    __shared__ float4 pts[PSZ];  // 16 KB: x,y,z,xx
    const int tid = threadIdx.x;
    const int blk = blockIdx.x;
    const int p = blk & 3;
    const int g = (blk >> 2) & 15;
    const int b = blk >> 6;
    const float* xb = xyz + (size_t)b * (3 * NN);

    for (int j = tid; j < PSZ; j += 256) {
        int i = (p << 10) | j;
        float x = xb[i], y = xb[NN + i], z = xb[2 * NN + i];
        float xx = ((x * x) + (y * y)) + (z * z);  // rn (contract off)
        pts[j] = make_float4(x, y, z, xx);
    }
    const int q = (g << 8) | tid;  // query within batch
    const float qx = xb[q], qy = xb[NN + q], qz = xb[2 * NN + q];
    const float qxx = ((qx * qx) + (qy * qy)) + (qz * qz);
    __syncthreads();

    H_DECL
#pragma unroll 2
    for (int j = 0; j < PSZ; ++j) {
        float4 cp = pts[j];
        float dot = __builtin_fmaf(qz, cp.z, __builtin_fmaf(qy, cp.y, qx * cp.x));
        float pd = ((dot + dot) - qxx) - cp.w;
        INS_CHAIN
    }

    const int qg = (b << 12) | q;  // global query
    float* vp = val_buf + (size_t)(p * KNN) * NQ + qg;
#define ST(t, ht) vp[(size_t)(t) * NQ] = ht;
    ST(0,h00) ST(1,h01) ST(2,h02) ST(3,h03) ST(4,h04) ST(5,h05) ST(6,h06)
    ST(7,h07) ST(8,h08) ST(9,h09) ST(10,h10) ST(11,h11) ST(12,h12) ST(13,h13)
    ST(14,h14) ST(15,h15) ST(16,h16) ST(17,h17) ST(18,h18) ST(19,h19)
    ST(20,h20) ST(21,h21) ST(22,h22) ST(23,h23) ST(24,h24) ST(25,h25)
    ST(26,h26) ST(27,h27) ST(28,h28) ST(29,h29) ST(30,h30) ST(31,h31)
#undef ST
}

// --------------------------------------------------------------------------
// B: LDS-free 4-way merge. One thread per query, 256-thr blocks, full
// occupancy. Lists are walked sequentially; loads coalesced across qg.
// Strict counts re-read only the taken prefixes (<=32 loads, L1/L2-hot).
// --------------------------------------------------------------------------
__global__ __launch_bounds__(256) void knn_merge_kernel(
        const float* __restrict__ val_buf, float* __restrict__ T_buf,
        int* __restrict__ pack_buf) {
    const int qg = blockIdx.x * 256 + threadIdx.x;
    const float* vp = val_buf + qg;  // list p elem t at vp[(p*32+t)*NQ]

    int i0 = 0, i1 = 0, i2 = 0, i3 = 0;
    float v0 = vp[0];
    float v1 = vp[(size_t)32 * NQ];
    float v2 = vp[(size_t)64 * NQ];
    float v3 = vp[(size_t)96 * NQ];
    float T = -FLT_MAX;
    for (int s = 0; s < 32; ++s) {
        float best = v0; int bp = 0;
        if (v1 > best) { best = v1; bp = 1; }   // strict: ties keep lower p
        if (v2 > best) { best = v2; bp = 2; }
        if (v3 > best) { best = v3; bp = 3; }
        T = best;
        if (bp == 0)      { ++i0; v0 = (i0 < 32) ? vp[(size_t)i0 * NQ]        : -FLT_MAX; }
        else if (bp == 1) { ++i1; v1 = (i1 < 32) ? vp[(size_t)(32 + i1) * NQ] : -FLT_MAX; }
        else if (bp == 2) { ++i2; v2 = (i2 < 32) ? vp[(size_t)(64 + i2) * NQ] : -FLT_MAX; }
        else              { ++i3; v3 = (i3 < 32) ? vp[(size_t)(96 + i3) * NQ] : -FLT_MAX; }
    }
    int s0 = 0, s1 = 0, s2 = 0, s3 = 0;
    for (int t = 0; t < i0; ++t) s0 += (vp[(size_t)t * NQ] > T);
    for (int t = 0; t < i1; ++t) s1 += (vp[(size_t)(32 + t) * NQ] > T);
    for (int t = 0; t < i2; ++t) s2 += (vp[(size_t)(64 + t) * NQ] > T);
    for (int t = 0; t < i3; ++t) s3 += (vp[(size_t)(96 + t) * NQ] > T);

    T_buf[qg] = T;
    int base = 0;
    pack_buf[qg * 4 + 0] = base | (s0 << 8) | (i0 << 16); base += i0;
    pack_buf[qg * 4 + 1] = base | (s1 << 8) | (i1 << 16); base += i1;
    pack_buf[qg * 4 + 2] = base | (s2 << 8) | (i2 << 16); base += i2;
    pack_buf[qg * 4 + 3] = base | (s3 << 8) | (i3 << 16);
}

// --------------------------------------------------------------------------
// C: same shape as A; re-scan with T, emit batch-local indices.
// --------------------------------------------------------------------------
__global__ __launch_bounds__(256) void knn_emit_kernel(
        const float* __restrict__ xyz, const float* __restrict__ T_buf,
        const int* __restrict__ pack_buf, int* __restrict__ idx_out) {
#pragma clang fp contract(off)
    __shared__ float4 pts[PSZ];
    const int tid = threadIdx.x;
    const int blk = blockIdx.x;
    const int p = blk & 3;
    const int g = (blk >> 2) & 15;
    const int b = blk >> 6;
    const float* xb = xyz + (size_t)b * (3 * NN);

    for (int j = tid; j < PSZ; j += 256) {
        int i = (p << 10) | j;
        float x = xb[i], y = xb[NN + i], z = xb[2 * NN + i];
        float xx = ((x * x) + (y * y)) + (z * z);
        pts[j] = make_float4(x, y, z, xx);
    }
    const int q = (g << 8) | tid;
    const float qx = xb[q], qy = xb[NN + q], qz = xb[2 * NN + q];
    const float qxx = ((qx * qx) + (qy * qy)) + (qz * qz);
    __syncthreads();

    const int qg = (b << 12) | q;
    const float T = T_buf[qg];
    const int pk = pack_buf[qg * 4 + p];
    int slot = pk & 255;
    const int sp = (pk >> 8) & 255;
    const int np = (pk >> 16) & 255;
    int tie_slot = slot + sp;
    const int tie_end = slot + np;
    int* outp = idx_out + (size_t)qg * KNN;

    for (int j = 0; j < PSZ; ++j) {
        float4 cp = pts[j];
        float dot = __builtin_fmaf(qz, cp.z, __builtin_fmaf(qy, cp.y, qx * cp.x));
        float pd = ((dot + dot) - qxx) - cp.w;
        if (pd > T) {
            outp[slot++] = (p << 10) | j;
        } else if (pd == T && tie_slot < tie_end) {
            outp[tie_slot++] = (p << 10) | j;
        }
    }
}

// --------------------------------------------------------------------------
// gather: one wave per query, lane = channel; fp64 sigma accumulation.
// --------------------------------------------------------------------------
__global__ __launch_bounds__(256) void gather_minmax_kernel(
        const float* __restrict__ feats, const int* __restrict__ idx_in,
        float* __restrict__ mx_buf, float* __restrict__ mn_buf,
        double* __restrict__ partials) {
    const int tid = threadIdx.x;
    const int w = tid >> 6;
    const int lane = tid & 63;
    const int q = blockIdx.x * 4 + w;
    const int b = q >> 12;
    const float* fb = feats + (size_t)b * (NN * CC);
    const float center = feats[(size_t)q * CC + lane];
    const int* ip = idx_in + (size_t)q * KNN;

    float mx = -FLT_MAX, mn = FLT_MAX;
    double ss = 0.0;
#pragma unroll 4
    for (int k = 0; k < KNN; ++k) {
        int nb = ip[k];
        float v = fb[(size_t)nb * CC + lane];
        float off = v - center;
        mx = fmaxf(mx, off);
        mn = fminf(mn, off);
        double od = (double)off;
        ss = fma(od, od, ss);
    }
    mx_buf[(size_t)q * CC + lane] = mx;
    mn_buf[(size_t)q * CC + lane] = mn;

#pragma unroll
    for (int o = 32; o >= 1; o >>= 1) ss += __shfl_down(ss, o, 64);
    __shared__ double wsum[4];
    if (lane == 0) wsum[w] = ss;
    __syncthreads();
    if (tid == 0) partials[blockIdx.x] = (wsum[0] + wsum[1]) + (wsum[2] + wsum[3]);
}

__global__ __launch_bounds__(256) void sigma_kernel(const double* __restrict__ partials,
                                                    float* __restrict__ sigma) {
    __shared__ double red[256];
    double s = 0.0;
    for (int i = threadIdx.x; i < 16384; i += 256) s += partials[i];
    red[threadIdx.x] = s;
    __syncthreads();
    for (int o = 128; o >= 1; o >>= 1) {
        if (threadIdx.x < o) red[threadIdx.x] += red[threadIdx.x + o];
        __syncthreads();
    }
    if (threadIdx.x == 0) sigma[0] = (float)(red[0] * (1.0 / 134217728.0));
}

__global__ __launch_bounds__(256) void finalize_kernel(
        const float* __restrict__ mx_buf, const float* __restrict__ mn_buf,
        const float* __restrict__ alpha, const float* __restrict__ beta,
        const float* __restrict__ sigma, float* __restrict__ out) {
#pragma clang fp contract(off)
    const int e = blockIdx.x * 256 + threadIdx.x;
    const int c = e & (CC - 1);
    const float s = sigma[0] + 1e-5f;
    const float a = alpha[c];
    const float bt = beta[c];
    const float off = (a >= 0.f) ? mx_buf[e] : mn_buf[e];
    const float t = off / s;
    out[e] = (t * a) + bt;
}

extern "C" void kernel_launch(void* const* d_in, const int* in_sizes, int n_in,
                              void* d_out, int out_size, void* d_ws, size_t ws_size,
                              hipStream_t stream) {
    (void)in_sizes; (void)n_in; (void)out_size; (void)ws_size;
    const float* xyz   = (const float*)d_in[0];  // [16,3,4096]
    const float* feats = (const float*)d_in[1];  // [16,4096,64]
    const float* alpha = (const float*)d_in[2];  // [64]
    const float* beta  = (const float*)d_in[3];  // [64]
    float* out = (float*)d_out;                  // [16,4096,64]

    char* ws = (char*)d_ws;
    // Layout (aliased — val_buf is dead before gather writes mx/mn):
    int*    idx_buf  = (int*)ws;                     // [0, 8MB)
    float*  val_buf  = (float*)(ws + 8388608);       // [8MB, 40MB)  65536*128*4
    float*  mx_buf   = (float*)(ws + 8388608);       // alias  [8MB, 24MB)
    float*  mn_buf   = (float*)(ws + 25165824);      // alias  [24MB, 40MB)
    float*  T_buf    = (float*)(ws + 41943040);      // [40MB, +256KB)
    int*    pack_buf = (int*)(ws + 42205184);        // [+1MB)
    double* partials = (double*)(ws + 43253760);     // 16384*8 = 128KB
    float*  sigma    = (float*)(ws + 43384832);

    knn_select_kernel<<<BB * 16 * NPART, 256, 0, stream>>>(xyz, val_buf);
    knn_merge_kernel<<<NQ / 256, 256, 0, stream>>>(val_buf, T_buf, pack_buf);
    knn_emit_kernel<<<BB * 16 * NPART, 256, 0, stream>>>(xyz, T_buf, pack_buf, idx_buf);
    gather_minmax_kernel<<<NQ / 4, 256, 0, stream>>>(feats, idx_buf, mx_buf,
                                                     mn_buf, partials);
    sigma_kernel<<<1, 256, 0, stream>>>(partials, sigma);
    finalize_kernel<<<(NQ * CC) / 256, 256, 0, stream>>>(mx_buf, mn_buf, alpha,
                                                         beta, sigma, out);
}

// Round 9
// 463.778 us; speedup vs baseline: 1.2668x; 1.2668x over previous
//
#include <hip/hip_runtime.h>
#include <float.h>

#define BB 16
#define NN 4096
#define CC 64
#define KNN 32
#define NSLICE 8    // select slices per query
#define SSZ 512     // NN / NSLICE
#define CKEEP 18    // kept per slice; P(Bin(32,1/8)>18) ~ 4e-9
#define NPART 4     // emit partitions (unchanged interface)
#define PSZ 1024
#define NQ 65536

// ===========================================================================
// KNN, reference arithmetic VARIANT V2 (verified bit-compatible since R4):
//   dot = fma(z,z', fma(y,y', x*x'));  xx = ((x*x + y*y) + z*z)  [rn, no fma]
//   pd  = ((dot+dot) - xx_q) - xx_c    [left-assoc rn]
//
// R9: R5-R8 established select's floor at 165 cyc/iter for a 32-deep med3
// chain across 3 codegen variants and 2 register homes => v_med3_f32 issues
// at ~4.6 cyc (half-rate VOP3). Algorithmic fix: S=8 slices keep top-18 each;
// merge certifies exactness (all slice boundaries m_s < T) and flags the
// ~2e-3-probability violation to an exact per-query fallback kernel.
// ===========================================================================

#define M3 __builtin_amdgcn_fmed3f

// 18-deep descending insert: h17=med3(pd,h17,h16) ... h00=max(h00,pd)
#define CHAIN18 \
  h17=M3(pd,h17,h16); h16=M3(pd,h16,h15); h15=M3(pd,h15,h14); \
  h14=M3(pd,h14,h13); h13=M3(pd,h13,h12); h12=M3(pd,h12,h11); \
  h11=M3(pd,h11,h10); h10=M3(pd,h10,h09); h09=M3(pd,h09,h08); \
  h08=M3(pd,h08,h07); h07=M3(pd,h07,h06); h06=M3(pd,h06,h05); \
  h05=M3(pd,h05,h04); h04=M3(pd,h04,h03); h03=M3(pd,h03,h02); \
  h02=M3(pd,h02,h01); h01=M3(pd,h01,h00); h00=fmaxf(h00,pd);

#define H18_DECL \
  float h00=-FLT_MAX,h01=-FLT_MAX,h02=-FLT_MAX,h03=-FLT_MAX,h04=-FLT_MAX, \
        h05=-FLT_MAX,h06=-FLT_MAX,h07=-FLT_MAX,h08=-FLT_MAX,h09=-FLT_MAX, \
        h10=-FLT_MAX,h11=-FLT_MAX,h12=-FLT_MAX,h13=-FLT_MAX,h14=-FLT_MAX, \
        h15=-FLT_MAX,h16=-FLT_MAX,h17=-FLT_MAX;

// --------------------------------------------------------------------------
// A: select. grid 2048 = (b<<7)|(g<<3)|s, 256 thr = 256 queries.
// Slice s covers candidates [s*512, (s+1)*512). LDS 8 KB.
// --------------------------------------------------------------------------
__global__ __launch_bounds__(256) void knn_select_kernel(
        const float* __restrict__ xyz, float* __restrict__ val_buf) {
#pragma clang fp contract(off)
    __shared__ float4 pts[SSZ];
    const int tid = threadIdx.x;
    const int blk = blockIdx.x;
    const int s = blk & 7;
    const int g = (blk >> 3) & 15;
    const int b = blk >> 7;
    const float* xb = xyz + (size_t)b * (3 * NN);

    for (int j = tid; j < SSZ; j += 256) {
        int i = (s << 9) | j;
        float x = xb[i], y = xb[NN + i], z = xb[2 * NN + i];
        float xx = ((x * x) + (y * y)) + (z * z);  // rn (contract off)
        pts[j] = make_float4(x, y, z, xx);
    }
    const int q = (g << 8) | tid;
    const float qx = xb[q], qy = xb[NN + q], qz = xb[2 * NN + q];
    const float qxx = ((qx * qx) + (qy * qy)) + (qz * qz);
    __syncthreads();

    H18_DECL
#pragma unroll 2
    for (int j = 0; j < SSZ; ++j) {
        float4 cp = pts[j];
        float dot = __builtin_fmaf(qz, cp.z, __builtin_fmaf(qy, cp.y, qx * cp.x));
        float pd = ((dot + dot) - qxx) - cp.w;
        CHAIN18
    }

    const int qg = (b << 12) | q;
    float* vp = val_buf + (size_t)(s * CKEEP) * NQ + qg;  // desc order t=0..17
#define ST(t, ht) vp[(size_t)(t) * NQ] = ht;
    ST(0,h00) ST(1,h01) ST(2,h02) ST(3,h03) ST(4,h04) ST(5,h05)
    ST(6,h06) ST(7,h07) ST(8,h08) ST(9,h09) ST(10,h10) ST(11,h11)
    ST(12,h12) ST(13,h13) ST(14,h14) ST(15,h15) ST(16,h16) ST(17,h17)
#undef ST
}

// --------------------------------------------------------------------------
// B: merge. 64-thr blocks; stage 144 values/query to LDS (stride 145);
// 8-head sequential merge -> T (32nd largest of union); certificate:
// every slice's 18th value m_s < T, else flag for exact fallback.
// Counts per emit-partition (slice s -> partition s>>1) exact when unflagged.
// --------------------------------------------------------------------------
__global__ __launch_bounds__(64) void knn_merge_kernel(
        const float* __restrict__ val_buf, float* __restrict__ T_buf,
        int* __restrict__ pack_buf, unsigned char* __restrict__ flag_buf) {
    __shared__ float lv[64 * 145];  // 37120 B
    const int tid = threadIdx.x;
    const int qg = blockIdx.x * 64 + tid;
    float* my = lv + tid * 145;
    for (int t = 0; t < 144; ++t) my[t] = val_buf[(size_t)t * NQ + qg];

    int p0=0,p1=0,p2=0,p3=0,p4=0,p5=0,p6=0,p7=0;
    float v0=my[0], v1=my[18], v2=my[36], v3=my[54];
    float v4=my[72], v5=my[90], v6=my[108], v7=my[126];
    float T = -FLT_MAX;
    for (int step = 0; step < 32; ++step) {
        float best = v0; int bp = 0;
        if (v1 > best) { best = v1; bp = 1; }
        if (v2 > best) { best = v2; bp = 2; }
        if (v3 > best) { best = v3; bp = 3; }
        if (v4 > best) { best = v4; bp = 4; }
        if (v5 > best) { best = v5; bp = 5; }
        if (v6 > best) { best = v6; bp = 6; }
        if (v7 > best) { best = v7; bp = 7; }
        T = best;
        if      (bp==0) { ++p0; v0 = (p0<18)?my[p0]      :-FLT_MAX; }
        else if (bp==1) { ++p1; v1 = (p1<18)?my[18+p1]   :-FLT_MAX; }
        else if (bp==2) { ++p2; v2 = (p2<18)?my[36+p2]   :-FLT_MAX; }
        else if (bp==3) { ++p3; v3 = (p3<18)?my[54+p3]   :-FLT_MAX; }
        else if (bp==4) { ++p4; v4 = (p4<18)?my[72+p4]   :-FLT_MAX; }
        else if (bp==5) { ++p5; v5 = (p5<18)?my[90+p5]   :-FLT_MAX; }
        else if (bp==6) { ++p6; v6 = (p6<18)?my[108+p6]  :-FLT_MAX; }
        else            { ++p7; v7 = (p7<18)?my[126+p7]  :-FLT_MAX; }
    }

    int gt0=0,gt1=0,gt2=0,gt3=0, eq0=0,eq1=0,eq2=0,eq3=0;
    bool flag = false;
    for (int sl = 0; sl < 8; ++sl) {
        const int base = sl * 18;
        int g_ = 0, e_ = 0;
        for (int t = 0; t < 18; ++t) {
            float v = my[base + t];
            g_ += (v > T); e_ += (v == T);
        }
        const int gp = sl >> 1;
        if      (gp == 0) { gt0 += g_; eq0 += e_; }
        else if (gp == 1) { gt1 += g_; eq1 += e_; }
        else if (gp == 2) { gt2 += g_; eq2 += e_; }
        else              { gt3 += g_; eq3 += e_; }
        flag = flag || (my[base + 17] >= T);  // certificate violation
    }

    T_buf[qg] = T;
    flag_buf[qg] = flag ? 1 : 0;
    int budget = 32 - (gt0 + gt1 + gt2 + gt3);
    int t0 = min(eq0, budget); budget -= t0;
    int t1 = min(eq1, budget); budget -= t1;
    int t2 = min(eq2, budget); budget -= t2;
    int t3 = min(eq3, budget);
    int base = 0;
    pack_buf[qg*4+0] = base | (gt0<<8) | ((gt0+t0)<<16); base += gt0+t0;
    pack_buf[qg*4+1] = base | (gt1<<8) | ((gt1+t1)<<16); base += gt1+t1;
    pack_buf[qg*4+2] = base | (gt2<<8) | ((gt2+t2)<<16); base += gt2+t2;
    pack_buf[qg*4+3] = base | (gt3<<8) | ((gt3+t3)<<16);
}

// --------------------------------------------------------------------------
// B2: exact fallback for flagged queries (expected: zero). Full 4096-scan
// with 32-deep chain (V2 arithmetic), exact T + per-partition counts.
// --------------------------------------------------------------------------
#define CHAIN32 \
  k31=M3(pd,k31,k30); k30=M3(pd,k30,k29); k29=M3(pd,k29,k28); k28=M3(pd,k28,k27); \
  k27=M3(pd,k27,k26); k26=M3(pd,k26,k25); k25=M3(pd,k25,k24); k24=M3(pd,k24,k23); \
  k23=M3(pd,k23,k22); k22=M3(pd,k22,k21); k21=M3(pd,k21,k20); k20=M3(pd,k20,k19); \
  k19=M3(pd,k19,k18); k18=M3(pd,k18,k17); k17=M3(pd,k17,k16); k16=M3(pd,k16,k15); \
  k15=M3(pd,k15,k14); k14=M3(pd,k14,k13); k13=M3(pd,k13,k12); k12=M3(pd,k12,k11); \
  k11=M3(pd,k11,k10); k10=M3(pd,k10,k09); k09=M3(pd,k09,k08); k08=M3(pd,k08,k07); \
  k07=M3(pd,k07,k06); k06=M3(pd,k06,k05); k05=M3(pd,k05,k04); k04=M3(pd,k04,k03); \
  k03=M3(pd,k03,k02); k02=M3(pd,k02,k01); k01=M3(pd,k01,k00); k00=fmaxf(k00,pd);

__global__ __launch_bounds__(256) void knn_fallback_kernel(
        const float* __restrict__ xyz, const unsigned char* __restrict__ flag_buf,
        float* __restrict__ T_buf, int* __restrict__ pack_buf) {
#pragma clang fp contract(off)
    const int qg = blockIdx.x * 256 + threadIdx.x;
    if (!flag_buf[qg]) return;
    const int b = qg >> 12;
    const int q = qg & (NN - 1);
    const float* xb = xyz + (size_t)b * (3 * NN);
    const float qx = xb[q], qy = xb[NN + q], qz = xb[2 * NN + q];
    const float qxx = ((qx * qx) + (qy * qy)) + (qz * qz);

    float k00=-FLT_MAX,k01=-FLT_MAX,k02=-FLT_MAX,k03=-FLT_MAX,k04=-FLT_MAX,
          k05=-FLT_MAX,k06=-FLT_MAX,k07=-FLT_MAX,k08=-FLT_MAX,k09=-FLT_MAX,
          k10=-FLT_MAX,k11=-FLT_MAX,k12=-FLT_MAX,k13=-FLT_MAX,k14=-FLT_MAX,
          k15=-FLT_MAX,k16=-FLT_MAX,k17=-FLT_MAX,k18=-FLT_MAX,k19=-FLT_MAX,
          k20=-FLT_MAX,k21=-FLT_MAX,k22=-FLT_MAX,k23=-FLT_MAX,k24=-FLT_MAX,
          k25=-FLT_MAX,k26=-FLT_MAX,k27=-FLT_MAX,k28=-FLT_MAX,k29=-FLT_MAX,
          k30=-FLT_MAX,k31=-FLT_MAX;
    for (int j = 0; j < NN; ++j) {
        float x = xb[j], y = xb[NN + j], z = xb[2 * NN + j];
        float xxc = ((x * x) + (y * y)) + (z * z);
        float dot = __builtin_fmaf(qz, z, __builtin_fmaf(qy, y, qx * x));
        float pd = ((dot + dot) - qxx) - xxc;
        CHAIN32
    }
    const float T = k31;

    int gt[4] = {0,0,0,0}, eq[4] = {0,0,0,0};
    for (int p = 0; p < 4; ++p) {
        int g_ = 0, e_ = 0;
        for (int j = p * PSZ; j < (p + 1) * PSZ; ++j) {
            float x = xb[j], y = xb[NN + j], z = xb[2 * NN + j];
            float xxc = ((x * x) + (y * y)) + (z * z);
            float dot = __builtin_fmaf(qz, z, __builtin_fmaf(qy, y, qx * x));
            float pd = ((dot + dot) - qxx) - xxc;
            g_ += (pd > T); e_ += (pd == T);
        }
        gt[p] = g_; eq[p] = e_;
    }
    T_buf[qg] = T;
    int budget = 32 - (gt[0] + gt[1] + gt[2] + gt[3]);
    int base = 0;
    for (int p = 0; p < 4; ++p) {
        int tp = min(eq[p], budget); budget -= tp;
        pack_buf[qg*4+p] = base | (gt[p]<<8) | ((gt[p]+tp)<<16);
        base += gt[p] + tp;
    }
}

// --------------------------------------------------------------------------
// C: emit (unchanged): re-scan 4 partitions of 1024 with T, write indices.
// --------------------------------------------------------------------------
__global__ __launch_bounds__(256) void knn_emit_kernel(
        const float* __restrict__ xyz, const float* __restrict__ T_buf,
        const int* __restrict__ pack_buf, int* __restrict__ idx_out) {
#pragma clang fp contract(off)
    __shared__ float4 pts[PSZ];
    const int tid = threadIdx.x;
    const int blk = blockIdx.x;
    const int p = blk & 3;
    const int g = (blk >> 2) & 15;
    const int b = blk >> 6;
    const float* xb = xyz + (size_t)b * (3 * NN);

    for (int j = tid; j < PSZ; j += 256) {
        int i = (p << 10) | j;
        float x = xb[i], y = xb[NN + i], z = xb[2 * NN + i];
        float xx = ((x * x) + (y * y)) + (z * z);
        pts[j] = make_float4(x, y, z, xx);
    }
    const int q = (g << 8) | tid;
    const float qx = xb[q], qy = xb[NN + q], qz = xb[2 * NN + q];
    const float qxx = ((qx * qx) + (qy * qy)) + (qz * qz);
    __syncthreads();

    const int qg = (b << 12) | q;
    const float T = T_buf[qg];
    const int pk = pack_buf[qg * 4 + p];
    int slot = pk & 255;
    const int sp = (pk >> 8) & 255;
    const int np = (pk >> 16) & 255;
    int tie_slot = slot + sp;
    const int tie_end = slot + np;
    int* outp = idx_out + (size_t)qg * KNN;

    for (int j = 0; j < PSZ; ++j) {
        float4 cp = pts[j];
        float dot = __builtin_fmaf(qz, cp.z, __builtin_fmaf(qy, cp.y, qx * cp.x));
        float pd = ((dot + dot) - qxx) - cp.w;
        if (pd > T) {
            outp[slot++] = (p << 10) | j;
        } else if (pd == T && tie_slot < tie_end) {
            outp[tie_slot++] = (p << 10) | j;
        }
    }
}

// --------------------------------------------------------------------------
// gather / sigma / finalize: unchanged.
// --------------------------------------------------------------------------
__global__ __launch_bounds__(256) void gather_minmax_kernel(
        const float* __restrict__ feats, const int* __restrict__ idx_in,
        float* __restrict__ mx_buf, float* __restrict__ mn_buf,
        double* __restrict__ partials) {
    const int tid = threadIdx.x;
    const int w = tid >> 6;
    const int lane = tid & 63;
    const int q = blockIdx.x * 4 + w;
    const int b = q >> 12;
    const float* fb = feats + (size_t)b * (NN * CC);
    const float center = feats[(size_t)q * CC + lane];
    const int* ip = idx_in + (size_t)q * KNN;

    float mx = -FLT_MAX, mn = FLT_MAX;
    double ss = 0.0;
#pragma unroll 4
    for (int k = 0; k < KNN; ++k) {
        int nb = ip[k];
        float v = fb[(size_t)nb * CC + lane];
        float off = v - center;
        mx = fmaxf(mx, off);
        mn = fminf(mn, off);
        double od = (double)off;
        ss = fma(od, od, ss);
    }
    mx_buf[(size_t)q * CC + lane] = mx;
    mn_buf[(size_t)q * CC + lane] = mn;

#pragma unroll
    for (int o = 32; o >= 1; o >>= 1) ss += __shfl_down(ss, o, 64);
    __shared__ double wsum[4];
    if (lane == 0) wsum[w] = ss;
    __syncthreads();
    if (tid == 0) partials[blockIdx.x] = (wsum[0] + wsum[1]) + (wsum[2] + wsum[3]);
}

__global__ __launch_bounds__(256) void sigma_kernel(const double* __restrict__ partials,
                                                    float* __restrict__ sigma) {
    __shared__ double red[256];
    double s = 0.0;
    for (int i = threadIdx.x; i < 16384; i += 256) s += partials[i];
    red[threadIdx.x] = s;
    __syncthreads();
    for (int o = 128; o >= 1; o >>= 1) {
        if (threadIdx.x < o) red[threadIdx.x] += red[threadIdx.x + o];
        __syncthreads();
    }
    if (threadIdx.x == 0) sigma[0] = (float)(red[0] * (1.0 / 134217728.0));
}

__global__ __launch_bounds__(256) void finalize_kernel(
        const float* __restrict__ mx_buf, const float* __restrict__ mn_buf,
        const float* __restrict__ alpha, const float* __restrict__ beta,
        const float* __restrict__ sigma, float* __restrict__ out) {
#pragma clang fp contract(off)
    const int e = blockIdx.x * 256 + threadIdx.x;
    const int c = e & (CC - 1);
    const float s = sigma[0] + 1e-5f;
    const float a = alpha[c];
    const float bt = beta[c];
    const float off = (a >= 0.f) ? mx_buf[e] : mn_buf[e];
    const float t = off / s;
    out[e] = (t * a) + bt;
}

extern "C" void kernel_launch(void* const* d_in, const int* in_sizes, int n_in,
                              void* d_out, int out_size, void* d_ws, size_t ws_size,
                              hipStream_t stream) {
    (void)in_sizes; (void)n_in; (void)out_size; (void)ws_size;
    const float* xyz   = (const float*)d_in[0];  // [16,3,4096]
    const float* feats = (const float*)d_in[1];  // [16,4096,64]
    const float* alpha = (const float*)d_in[2];  // [64]
    const float* beta  = (const float*)d_in[3];  // [64]
    float* out = (float*)d_out;                  // [16,4096,64]

    char* ws = (char*)d_ws;
    // Lifetimes: val(select->merge) | idx(emit->gather) mx,mn(gather->finalize)
    // alias val region; T/pack(merge/fallback->emit) reused for partials after.
    float*  val_buf  = (float*)ws;                   // [0, 37,748,736)
    int*    idx_buf  = (int*)ws;                     // alias [0, 8.4MB)  after merge
    float*  mx_buf   = (float*)(ws + 8388608);       // alias [8.4, 25.2MB)
    float*  mn_buf   = (float*)(ws + 25165824);      // [25.2, 41.9MB)
    float*  T_buf    = (float*)(ws + 41943040);      // 256 KB
    int*    pack_buf = (int*)(ws + 42205184);        // 1 MB
    unsigned char* flag_buf = (unsigned char*)(ws + 43253760);  // 64 KB
    double* partials = (double*)(ws + 41943040);     // alias T_buf (dead post-emit)
    float*  sigma    = (float*)(ws + 42074112);      // after partials

    knn_select_kernel<<<BB * 16 * NSLICE, 256, 0, stream>>>(xyz, val_buf);
    knn_merge_kernel<<<NQ / 64, 64, 0, stream>>>(val_buf, T_buf, pack_buf, flag_buf);
    knn_fallback_kernel<<<NQ / 256, 256, 0, stream>>>(xyz, flag_buf, T_buf, pack_buf);
    knn_emit_kernel<<<BB * 16 * NPART, 256, 0, stream>>>(xyz, T_buf, pack_buf, idx_buf);
    gather_minmax_kernel<<<NQ / 4, 256, 0, stream>>>(feats, idx_buf, mx_buf,
                                                     mn_buf, partials);
    sigma_kernel<<<1, 256, 0, stream>>>(partials, sigma);
    finalize_kernel<<<(NQ * CC) / 256, 256, 0, stream>>>(mx_buf, mn_buf, alpha,
                                                         beta, sigma, out);
}

// Round 10
// 446.515 us; speedup vs baseline: 1.3158x; 1.0387x over previous
//
#include <hip/hip_runtime.h>
#include <float.h>

#define BB 16
#define NN 4096
#define CC 64
#define KNN 32
#define NSLICE 8    // select slices per query
#define SSZ 512     // NN / NSLICE
#define CKEEP 16    // kept per slice; P(Bin(32,1/8)>=16) ~ 2.5e-7/slice
#define NPART 4     // emit partitions
#define PSZ 1024
#define NQ 65536

// ===========================================================================
// KNN, reference arithmetic VARIANT V2 (verified bit-compatible since R4):
//   dot = fma(z,z', fma(y,y', x*x'));  xx = ((x*x + y*y) + z*z)  [rn, no fma]
//   pd  = ((dot+dot) - qxx) - xx_c     [left-assoc rn]
//
// R10: measured med3 cost slope = 4.3 cyc each (R8: 32-chain 165 cyc/iter,
// R9: 18-chain 105 cyc/iter; occupancy-independent => issue-bound; 3-src
// VOP3 = 2 issue slots). Chain shrunk to 16 (15 med3). Certificate (slice
// boundary my[15] >= T) flags ~0.13 queries/run to the exact fallback.
// ===========================================================================

#define M3 __builtin_amdgcn_fmed3f

// 16-deep descending insert: h15=med3(pd,h15,h14) ... h00=max(h00,pd)
#define CHAIN16 \
  h15=M3(pd,h15,h14); h14=M3(pd,h14,h13); h13=M3(pd,h13,h12); \
  h12=M3(pd,h12,h11); h11=M3(pd,h11,h10); h10=M3(pd,h10,h09); \
  h09=M3(pd,h09,h08); h08=M3(pd,h08,h07); h07=M3(pd,h07,h06); \
  h06=M3(pd,h06,h05); h05=M3(pd,h05,h04); h04=M3(pd,h04,h03); \
  h03=M3(pd,h03,h02); h02=M3(pd,h02,h01); h01=M3(pd,h01,h00); \
  h00=fmaxf(h00,pd);

#define H16_DECL \
  float h00=-FLT_MAX,h01=-FLT_MAX,h02=-FLT_MAX,h03=-FLT_MAX,h04=-FLT_MAX, \
        h05=-FLT_MAX,h06=-FLT_MAX,h07=-FLT_MAX,h08=-FLT_MAX,h09=-FLT_MAX, \
        h10=-FLT_MAX,h11=-FLT_MAX,h12=-FLT_MAX,h13=-FLT_MAX,h14=-FLT_MAX, \
        h15=-FLT_MAX;

// --------------------------------------------------------------------------
// A: select. grid 2048 = (b<<7)|(g<<3)|s, 256 thr = 256 queries. LDS 8 KB.
// --------------------------------------------------------------------------
__global__ __launch_bounds__(256) void knn_select_kernel(
        const float* __restrict__ xyz, float* __restrict__ val_buf) {
#pragma clang fp contract(off)
    __shared__ float4 pts[SSZ];
    const int tid = threadIdx.x;
    const int blk = blockIdx.x;
    const int s = blk & 7;
    const int g = (blk >> 3) & 15;
    const int b = blk >> 7;
    const float* xb = xyz + (size_t)b * (3 * NN);

    for (int j = tid; j < SSZ; j += 256) {
        int i = (s << 9) | j;
        float x = xb[i], y = xb[NN + i], z = xb[2 * NN + i];
        float xx = ((x * x) + (y * y)) + (z * z);  // rn (contract off)
        pts[j] = make_float4(x, y, z, xx);
    }
    const int q = (g << 8) | tid;
    const float qx = xb[q], qy = xb[NN + q], qz = xb[2 * NN + q];
    const float qxx = ((qx * qx) + (qy * qy)) + (qz * qz);
    __syncthreads();

    H16_DECL
#pragma unroll 4
    for (int j = 0; j < SSZ; ++j) {
        float4 cp = pts[j];
        float dot = __builtin_fmaf(qz, cp.z, __builtin_fmaf(qy, cp.y, qx * cp.x));
        float pd = ((dot + dot) - qxx) - cp.w;
        CHAIN16
    }

    const int qg = (b << 12) | q;
    float* vp = val_buf + (size_t)(s * CKEEP) * NQ + qg;  // desc order t=0..15
#define ST(t, ht) vp[(size_t)(t) * NQ] = ht;
    ST(0,h00) ST(1,h01) ST(2,h02) ST(3,h03) ST(4,h04) ST(5,h05)
    ST(6,h06) ST(7,h07) ST(8,h08) ST(9,h09) ST(10,h10) ST(11,h11)
    ST(12,h12) ST(13,h13) ST(14,h14) ST(15,h15)
#undef ST
}

// --------------------------------------------------------------------------
// B: merge. 64-thr blocks; stage 8x16=128 values/query to LDS (stride 129);
// 8-head sequential merge -> T (32nd largest); certificate: every slice's
// 16th value < T, else flag for exact fallback. Counts per emit-partition
// (slice s -> partition s>>1) exact when unflagged.
// --------------------------------------------------------------------------
__global__ __launch_bounds__(64) void knn_merge_kernel(
        const float* __restrict__ val_buf, float* __restrict__ T_buf,
        int* __restrict__ pack_buf, unsigned char* __restrict__ flag_buf) {
    __shared__ float lv[64 * 129];  // 33 KB
    const int tid = threadIdx.x;
    const int qg = blockIdx.x * 64 + tid;
    float* my = lv + tid * 129;
    for (int t = 0; t < 128; ++t) my[t] = val_buf[(size_t)t * NQ + qg];

    int p0=0,p1=0,p2=0,p3=0,p4=0,p5=0,p6=0,p7=0;
    float v0=my[0],  v1=my[16], v2=my[32], v3=my[48];
    float v4=my[64], v5=my[80], v6=my[96], v7=my[112];
    float T = -FLT_MAX;
    for (int step = 0; step < 32; ++step) {
        float best = v0; int bp = 0;
        if (v1 > best) { best = v1; bp = 1; }
        if (v2 > best) { best = v2; bp = 2; }
        if (v3 > best) { best = v3; bp = 3; }
        if (v4 > best) { best = v4; bp = 4; }
        if (v5 > best) { best = v5; bp = 5; }
        if (v6 > best) { best = v6; bp = 6; }
        if (v7 > best) { best = v7; bp = 7; }
        T = best;
        if      (bp==0) { ++p0; v0 = (p0<16)?my[p0]     :-FLT_MAX; }
        else if (bp==1) { ++p1; v1 = (p1<16)?my[16+p1]  :-FLT_MAX; }
        else if (bp==2) { ++p2; v2 = (p2<16)?my[32+p2]  :-FLT_MAX; }
        else if (bp==3) { ++p3; v3 = (p3<16)?my[48+p3]  :-FLT_MAX; }
        else if (bp==4) { ++p4; v4 = (p4<16)?my[64+p4]  :-FLT_MAX; }
        else if (bp==5) { ++p5; v5 = (p5<16)?my[80+p5]  :-FLT_MAX; }
        else if (bp==6) { ++p6; v6 = (p6<16)?my[96+p6]  :-FLT_MAX; }
        else            { ++p7; v7 = (p7<16)?my[112+p7] :-FLT_MAX; }
    }

    int gt0=0,gt1=0,gt2=0,gt3=0, eq0=0,eq1=0,eq2=0,eq3=0;
    bool flag = false;
    for (int sl = 0; sl < 8; ++sl) {
        const int base = sl * 16;
        int g_ = 0, e_ = 0;
        for (int t = 0; t < 16; ++t) {
            float v = my[base + t];
            g_ += (v > T); e_ += (v == T);
        }
        const int gp = sl >> 1;
        if      (gp == 0) { gt0 += g_; eq0 += e_; }
        else if (gp == 1) { gt1 += g_; eq1 += e_; }
        else if (gp == 2) { gt2 += g_; eq2 += e_; }
        else              { gt3 += g_; eq3 += e_; }
        flag = flag || (my[base + 15] >= T);  // certificate violation
    }

    T_buf[qg] = T;
    flag_buf[qg] = flag ? 1 : 0;
    int budget = 32 - (gt0 + gt1 + gt2 + gt3);
    int t0 = min(eq0, budget); budget -= t0;
    int t1 = min(eq1, budget); budget -= t1;
    int t2 = min(eq2, budget); budget -= t2;
    int t3 = min(eq3, budget);
    int base = 0;
    pack_buf[qg*4+0] = base | (gt0<<8) | ((gt0+t0)<<16); base += gt0+t0;
    pack_buf[qg*4+1] = base | (gt1<<8) | ((gt1+t1)<<16); base += gt1+t1;
    pack_buf[qg*4+2] = base | (gt2<<8) | ((gt2+t2)<<16); base += gt2+t2;
    pack_buf[qg*4+3] = base | (gt3<<8) | ((gt3+t3)<<16);
}

// --------------------------------------------------------------------------
// B2: exact fallback for flagged queries (expected ~0 active). Full scan,
// 32-deep chain, exact T + per-partition counts.
// --------------------------------------------------------------------------
#define CHAIN32 \
  k31=M3(pd,k31,k30); k30=M3(pd,k30,k29); k29=M3(pd,k29,k28); k28=M3(pd,k28,k27); \
  k27=M3(pd,k27,k26); k26=M3(pd,k26,k25); k25=M3(pd,k25,k24); k24=M3(pd,k24,k23); \
  k23=M3(pd,k23,k22); k22=M3(pd,k22,k21); k21=M3(pd,k21,k20); k20=M3(pd,k20,k19); \
  k19=M3(pd,k19,k18); k18=M3(pd,k18,k17); k17=M3(pd,k17,k16); k16=M3(pd,k16,k15); \
  k15=M3(pd,k15,k14); k14=M3(pd,k14,k13); k13=M3(pd,k13,k12); k12=M3(pd,k12,k11); \
  k11=M3(pd,k11,k10); k10=M3(pd,k10,k09); k09=M3(pd,k09,k08); k08=M3(pd,k08,k07); \
  k07=M3(pd,k07,k06); k06=M3(pd,k06,k05); k05=M3(pd,k05,k04); k04=M3(pd,k04,k03); \
  k03=M3(pd,k03,k02); k02=M3(pd,k02,k01); k01=M3(pd,k01,k00); k00=fmaxf(k00,pd);

__global__ __launch_bounds__(256) void knn_fallback_kernel(
        const float* __restrict__ xyz, const unsigned char* __restrict__ flag_buf,
        float* __restrict__ T_buf, int* __restrict__ pack_buf) {
#pragma clang fp contract(off)
    const int qg = blockIdx.x * 256 + threadIdx.x;
    if (!flag_buf[qg]) return;
    const int b = qg >> 12;
    const int q = qg & (NN - 1);
    const float* xb = xyz + (size_t)b * (3 * NN);
    const float qx = xb[q], qy = xb[NN + q], qz = xb[2 * NN + q];
    const float qxx = ((qx * qx) + (qy * qy)) + (qz * qz);

    float k00=-FLT_MAX,k01=-FLT_MAX,k02=-FLT_MAX,k03=-FLT_MAX,k04=-FLT_MAX,
          k05=-FLT_MAX,k06=-FLT_MAX,k07=-FLT_MAX,k08=-FLT_MAX,k09=-FLT_MAX,
          k10=-FLT_MAX,k11=-FLT_MAX,k12=-FLT_MAX,k13=-FLT_MAX,k14=-FLT_MAX,
          k15=-FLT_MAX,k16=-FLT_MAX,k17=-FLT_MAX,k18=-FLT_MAX,k19=-FLT_MAX,
          k20=-FLT_MAX,k21=-FLT_MAX,k22=-FLT_MAX,k23=-FLT_MAX,k24=-FLT_MAX,
          k25=-FLT_MAX,k26=-FLT_MAX,k27=-FLT_MAX,k28=-FLT_MAX,k29=-FLT_MAX,
          k30=-FLT_MAX,k31=-FLT_MAX;
    for (int j = 0; j < NN; ++j) {
        float x = xb[j], y = xb[NN + j], z = xb[2 * NN + j];
        float xxc = ((x * x) + (y * y)) + (z * z);
        float dot = __builtin_fmaf(qz, z, __builtin_fmaf(qy, y, qx * x));
        float pd = ((dot + dot) - qxx) - xxc;
        CHAIN32
    }
    const float T = k31;

    int gt[4] = {0,0,0,0}, eq[4] = {0,0,0,0};
    for (int p = 0; p < 4; ++p) {
        int g_ = 0, e_ = 0;
        for (int j = p * PSZ; j < (p + 1) * PSZ; ++j) {
            float x = xb[j], y = xb[NN + j], z = xb[2 * NN + j];
            float xxc = ((x * x) + (y * y)) + (z * z);
            float dot = __builtin_fmaf(qz, z, __builtin_fmaf(qy, y, qx * x));
            float pd = ((dot + dot) - qxx) - xxc;
            g_ += (pd > T); e_ += (pd == T);
        }
        gt[p] = g_; eq[p] = e_;
    }
    T_buf[qg] = T;
    int budget = 32 - (gt[0] + gt[1] + gt[2] + gt[3]);
    int base = 0;
    for (int p = 0; p < 4; ++p) {
        int tp = min(eq[p], budget); budget -= tp;
        pack_buf[qg*4+p] = base | (gt[p]<<8) | ((gt[p]+tp)<<16);
        base += gt[p] + tp;
    }
}

// --------------------------------------------------------------------------
// C: emit: re-scan 4 partitions of 1024 with T, write indices.
// --------------------------------------------------------------------------
__global__ __launch_bounds__(256) void knn_emit_kernel(
        const float* __restrict__ xyz, const float* __restrict__ T_buf,
        const int* __restrict__ pack_buf, int* __restrict__ idx_out) {
#pragma clang fp contract(off)
    __shared__ float4 pts[PSZ];
    const int tid = threadIdx.x;
    const int blk = blockIdx.x;
    const int p = blk & 3;
    const int g = (blk >> 2) & 15;
    const int b = blk >> 6;
    const float* xb = xyz + (size_t)b * (3 * NN);

    for (int j = tid; j < PSZ; j += 256) {
        int i = (p << 10) | j;
        float x = xb[i], y = xb[NN + i], z = xb[2 * NN + i];
        float xx = ((x * x) + (y * y)) + (z * z);
        pts[j] = make_float4(x, y, z, xx);
    }
    const int q = (g << 8) | tid;
    const float qx = xb[q], qy = xb[NN + q], qz = xb[2 * NN + q];
    const float qxx = ((qx * qx) + (qy * qy)) + (qz * qz);
    __syncthreads();

    const int qg = (b << 12) | q;
    const float T = T_buf[qg];
    const int pk = pack_buf[qg * 4 + p];
    int slot = pk & 255;
    const int sp = (pk >> 8) & 255;
    const int np = (pk >> 16) & 255;
    int tie_slot = slot + sp;
    const int tie_end = slot + np;
    int* outp = idx_out + (size_t)qg * KNN;

#pragma unroll 2
    for (int j = 0; j < PSZ; ++j) {
        float4 cp = pts[j];
        float dot = __builtin_fmaf(qz, cp.z, __builtin_fmaf(qy, cp.y, qx * cp.x));
        float pd = ((dot + dot) - qxx) - cp.w;
        if (pd > T) {
            outp[slot++] = (p << 10) | j;
        } else if (pd == T && tie_slot < tie_end) {
            outp[tie_slot++] = (p << 10) | j;
        }
    }
}

// --------------------------------------------------------------------------
// gather / sigma / finalize: unchanged.
// --------------------------------------------------------------------------
__global__ __launch_bounds__(256) void gather_minmax_kernel(
        const float* __restrict__ feats, const int* __restrict__ idx_in,
        float* __restrict__ mx_buf, float* __restrict__ mn_buf,
        double* __restrict__ partials) {
    const int tid = threadIdx.x;
    const int w = tid >> 6;
    const int lane = tid & 63;
    const int q = blockIdx.x * 4 + w;
    const int b = q >> 12;
    const float* fb = feats + (size_t)b * (NN * CC);
    const float center = feats[(size_t)q * CC + lane];
    const int* ip = idx_in + (size_t)q * KNN;

    float mx = -FLT_MAX, mn = FLT_MAX;
    double ss = 0.0;
#pragma unroll 4
    for (int k = 0; k < KNN; ++k) {
        int nb = ip[k];
        float v = fb[(size_t)nb * CC + lane];
        float off = v - center;
        mx = fmaxf(mx, off);
        mn = fminf(mn, off);
        double od = (double)off;
        ss = fma(od, od, ss);
    }
    mx_buf[(size_t)q * CC + lane] = mx;
    mn_buf[(size_t)q * CC + lane] = mn;

#pragma unroll
    for (int o = 32; o >= 1; o >>= 1) ss += __shfl_down(ss, o, 64);
    __shared__ double wsum[4];
    if (lane == 0) wsum[w] = ss;
    __syncthreads();
    if (tid == 0) partials[blockIdx.x] = (wsum[0] + wsum[1]) + (wsum[2] + wsum[3]);
}

__global__ __launch_bounds__(256) void sigma_kernel(const double* __restrict__ partials,
                                                    float* __restrict__ sigma) {
    __shared__ double red[256];
    double s = 0.0;
    for (int i = threadIdx.x; i < 16384; i += 256) s += partials[i];
    red[threadIdx.x] = s;
    __syncthreads();
    for (int o = 128; o >= 1; o >>= 1) {
        if (threadIdx.x < o) red[threadIdx.x] += red[threadIdx.x + o];
        __syncthreads();
    }
    if (threadIdx.x == 0) sigma[0] = (float)(red[0] * (1.0 / 134217728.0));
}

__global__ __launch_bounds__(256) void finalize_kernel(
        const float* __restrict__ mx_buf, const float* __restrict__ mn_buf,
        const float* __restrict__ alpha, const float* __restrict__ beta,
        const float* __restrict__ sigma, float* __restrict__ out) {
#pragma clang fp contract(off)
    const int e = blockIdx.x * 256 + threadIdx.x;
    const int c = e & (CC - 1);
    const float s = sigma[0] + 1e-5f;
    const float a = alpha[c];
    const float bt = beta[c];
    const float off = (a >= 0.f) ? mx_buf[e] : mn_buf[e];
    const float t = off / s;
    out[e] = (t * a) + bt;
}

extern "C" void kernel_launch(void* const* d_in, const int* in_sizes, int n_in,
                              void* d_out, int out_size, void* d_ws, size_t ws_size,
                              hipStream_t stream) {
    (void)in_sizes; (void)n_in; (void)out_size; (void)ws_size;
    const float* xyz   = (const float*)d_in[0];  // [16,3,4096]
    const float* feats = (const float*)d_in[1];  // [16,4096,64]
    const float* alpha = (const float*)d_in[2];  // [64]
    const float* beta  = (const float*)d_in[3];  // [64]
    float* out = (float*)d_out;                  // [16,4096,64]

    char* ws = (char*)d_ws;
    // Lifetimes: val(select->merge) aliases idx/mx/mn (emit->finalize);
    // T/pack live merge->emit; partials alias T after emit.
    float*  val_buf  = (float*)ws;                   // [0, 33,554,432)
    int*    idx_buf  = (int*)ws;                     // alias [0, 8.4MB) post-merge
    float*  mx_buf   = (float*)(ws + 8388608);       // [8.4, 25.2MB)
    float*  mn_buf   = (float*)(ws + 25165824);      // [25.2, 41.9MB)
    float*  T_buf    = (float*)(ws + 41943040);      // 256 KB
    int*    pack_buf = (int*)(ws + 42205184);        // 1 MB
    unsigned char* flag_buf = (unsigned char*)(ws + 43253760);  // 64 KB
    double* partials = (double*)(ws + 41943040);     // alias T_buf (dead post-emit)
    float*  sigma    = (float*)(ws + 42074112);

    knn_select_kernel<<<BB * 16 * NSLICE, 256, 0, stream>>>(xyz, val_buf);
    knn_merge_kernel<<<NQ / 64, 64, 0, stream>>>(val_buf, T_buf, pack_buf, flag_buf);
    knn_fallback_kernel<<<NQ / 256, 256, 0, stream>>>(xyz, flag_buf, T_buf, pack_buf);
    knn_emit_kernel<<<BB * 16 * NPART, 256, 0, stream>>>(xyz, T_buf, pack_buf, idx_buf);
    gather_minmax_kernel<<<NQ / 4, 256, 0, stream>>>(feats, idx_buf, mx_buf,
                                                     mn_buf, partials);
    sigma_kernel<<<1, 256, 0, stream>>>(partials, sigma);
    finalize_kernel<<<(NQ * CC) / 256, 256, 0, stream>>>(mx_buf, mn_buf, alpha,
                                                         beta, sigma, out);
}